// Round 1
// baseline (506.374 us; speedup 1.0000x reference)
//
#include <hip/hip_runtime.h>
#include <math.h>

// Problem constants (fixed by setup_inputs): B=4, M=8192, D=512, N=128, P=1
#define B_ 4
#define M_ 8192
#define D_ 512
#define N_ 128
#define TOK (B_ * M_)          // 32768 token rows
#define MCHUNKS 8              // split-K chunks over M for xs

// Workspace layout (float offsets)
#define OFF_RN 0                               // [TOK] token inverse norms
#define OFF_PB (OFF_RN + TOK)                  // [D_*N_] scale-normalized phi (row-major d x n)
#define OFF_CS (OFF_PB + D_ * N_)              // [B_*N_] column sums of E (dispatch softmax denom)
#define OFF_XP (OFF_CS + B_ * N_)              // [MCHUNKS*B_*N_*D_] xs partials
#define OFF_YS (OFF_XP + MCHUNKS * B_ * N_ * D_) // [B_*N_*D_] expert outputs
#define OFF_E (OFF_YS + B_ * N_ * D_)          // [TOK*N_] E = exp(logits)

// ---------------------------------------------------------------------------
// K0: phi column norms -> pb[d][n] = phi[d][n] * scale / max(||phi[:,n]||, eps)
__global__ __launch_bounds__(128) void k_phinorm(const float* __restrict__ phi,
                                                 const float* __restrict__ scale,
                                                 float* __restrict__ pb) {
    __shared__ float sred[128];
    int n = blockIdx.x, tid = threadIdx.x;
    float ss = 0.f;
    for (int d = tid; d < D_; d += 128) {
        float v = phi[d * N_ + n];
        ss += v * v;
    }
    sred[tid] = ss;
    __syncthreads();
    for (int s = 64; s > 0; s >>= 1) {
        if (tid < s) sred[tid] += sred[tid + s];
        __syncthreads();
    }
    float sc = scale[0] / fmaxf(sqrtf(sred[0]), 1e-12f);
    for (int d = tid; d < D_; d += 128) pb[d * N_ + n] = phi[d * N_ + n] * sc;
}

// ---------------------------------------------------------------------------
// K1: token inverse norms. One wave (64 lanes) per token, 4 tokens/block.
__global__ __launch_bounds__(256) void k_rn(const float* __restrict__ x,
                                            float* __restrict__ rn) {
    int token = blockIdx.x * 4 + (threadIdx.x >> 6);
    int lane = threadIdx.x & 63;
    const float4* x4 = (const float4*)x;
    float4 a = x4[(size_t)token * 128 + lane];
    float4 c = x4[(size_t)token * 128 + 64 + lane];
    float ss = a.x * a.x + a.y * a.y + a.z * a.z + a.w * a.w +
               c.x * c.x + c.y * c.y + c.z * c.z + c.w * c.w;
#pragma unroll
    for (int off = 32; off > 0; off >>= 1) ss += __shfl_down(ss, off, 64);
    if (lane == 0) rn[token] = 1.0f / fmaxf(sqrtf(ss), 1e-12f);
}

// ---------------------------------------------------------------------------
// K2: logits GEMM + exp + column-sum atomics.
// E[r][n] = exp(rn[r] * sum_k x[r][k] * pb[k][n]),  r = global token row.
// Block: 64 token rows x all 128 n. 256 threads: ty=tid>>4 (m-group of 4),
// tx=tid&15 (n-group of 8). K-chunks of 16.
__global__ __launch_bounds__(256) void k_logits(const float* __restrict__ x,
                                                const float* __restrict__ pb,
                                                const float* __restrict__ rn,
                                                float* __restrict__ E,
                                                float* __restrict__ colsum) {
    __shared__ float At[16][64];   // [k][m], rn-scaled
    __shared__ float Bt[16][128];  // [k][n]
    __shared__ float scr[16][128];
    int tid = threadIdx.x;
    int r0 = blockIdx.x * 64;
    int ty = tid >> 4, tx = tid & 15;
    int lm = tid >> 2, lkq = tid & 3;  // A loader: row lm, 4-float chunk lkq
    float rnv = rn[r0 + lm];
    float acc[4][8];
#pragma unroll
    for (int i = 0; i < 4; i++)
#pragma unroll
        for (int j = 0; j < 8; j++) acc[i][j] = 0.f;

    for (int k0 = 0; k0 < D_; k0 += 16) {
        float4 a4 = *(const float4*)&x[(size_t)(r0 + lm) * D_ + k0 + lkq * 4];
        At[lkq * 4 + 0][lm] = a4.x * rnv;
        At[lkq * 4 + 1][lm] = a4.y * rnv;
        At[lkq * 4 + 2][lm] = a4.z * rnv;
        At[lkq * 4 + 3][lm] = a4.w * rnv;
#pragma unroll
        for (int i = 0; i < 2; i++) {
            int f = tid + i * 256;
            int kk = f >> 5, c4 = f & 31;
            *(float4*)&Bt[kk][c4 * 4] = *(const float4*)&pb[(size_t)(k0 + kk) * N_ + c4 * 4];
        }
        __syncthreads();
#pragma unroll
        for (int kk = 0; kk < 16; kk++) {
            float a[4], b[8];
#pragma unroll
            for (int i = 0; i < 4; i++) a[i] = At[kk][ty * 4 + i];
#pragma unroll
            for (int j = 0; j < 8; j++) b[j] = Bt[kk][tx * 8 + j];
#pragma unroll
            for (int i = 0; i < 4; i++)
#pragma unroll
                for (int j = 0; j < 8; j++) acc[i][j] += a[i] * b[j];
        }
        __syncthreads();
    }
    // exp + store E + per-column partials
    float csum[8];
#pragma unroll
    for (int j = 0; j < 8; j++) csum[j] = 0.f;
#pragma unroll
    for (int i = 0; i < 4; i++) {
#pragma unroll
        for (int j = 0; j < 8; j++) {
            float e = __expf(acc[i][j]);
            acc[i][j] = e;
            csum[j] += e;
        }
        int r = r0 + ty * 4 + i;
        float4 v0 = {acc[i][0], acc[i][1], acc[i][2], acc[i][3]};
        float4 v1 = {acc[i][4], acc[i][5], acc[i][6], acc[i][7]};
        *(float4*)&E[(size_t)r * N_ + tx * 8] = v0;
        *(float4*)&E[(size_t)r * N_ + tx * 8 + 4] = v1;
    }
#pragma unroll
    for (int j = 0; j < 8; j++) scr[ty][tx * 8 + j] = csum[j];
    __syncthreads();
    if (tid < 128) {
        float s = 0.f;
#pragma unroll
        for (int g = 0; g < 16; g++) s += scr[g][tid];
        int b = r0 >> 13;  // r0 / M_
        atomicAdd(&colsum[b * N_ + tid], s);
    }
}

// ---------------------------------------------------------------------------
// K3: xs partials. Block = (b, d-tile of 64, m-chunk of 1024), all 128 n.
// part[mc][b][n][d] = sum_{m in chunk} (E[m][n]*rn[m]) * x[m][d]
// 256 threads: ty=tid>>4 -> n = i*16+ty (i<8); tx=tid&15 -> d cols tx*4..+3.
__global__ __launch_bounds__(256) void k_xs(const float* __restrict__ x,
                                            const float* __restrict__ E,
                                            const float* __restrict__ rn,
                                            float* __restrict__ part) {
    __shared__ float Et[16][128];  // [m][n], rn-scaled
    __shared__ float xt[16][64];   // [m][d]
    int bi = blockIdx.x;
    int b = bi >> 6, dt = (bi >> 3) & 7, mc = bi & 7;
    int d0 = dt * 64;
    int rbase0 = b * M_ + mc * 1024;
    int tid = threadIdx.x;
    int ty = tid >> 4, tx = tid & 15;
    float acc[8][4];
#pragma unroll
    for (int i = 0; i < 8; i++)
#pragma unroll
        for (int j = 0; j < 4; j++) acc[i][j] = 0.f;

    for (int ms = 0; ms < 1024; ms += 16) {
        int rb = rbase0 + ms;
#pragma unroll
        for (int i = 0; i < 2; i++) {
            int f = tid + i * 256;
            int mm = f >> 5, c4 = f & 31;
            float4 v = *(const float4*)&E[(size_t)(rb + mm) * N_ + c4 * 4];
            float rr = rn[rb + mm];
            v.x *= rr; v.y *= rr; v.z *= rr; v.w *= rr;
            *(float4*)&Et[mm][c4 * 4] = v;
        }
        {
            int mm = tid >> 4, d4 = tid & 15;
            *(float4*)&xt[mm][d4 * 4] =
                *(const float4*)&x[(size_t)(rb + mm) * D_ + d0 + d4 * 4];
        }
        __syncthreads();
#pragma unroll
        for (int kk = 0; kk < 16; kk++) {
            float a[8], bb[4];
#pragma unroll
            for (int i = 0; i < 8; i++) a[i] = Et[kk][i * 16 + ty];
#pragma unroll
            for (int j = 0; j < 4; j++) bb[j] = xt[kk][tx * 4 + j];
#pragma unroll
            for (int i = 0; i < 8; i++)
#pragma unroll
                for (int j = 0; j < 4; j++) acc[i][j] += a[i] * bb[j];
        }
        __syncthreads();
    }
#pragma unroll
    for (int i = 0; i < 8; i++) {
        int n = i * 16 + ty;
        float4 v = {acc[i][0], acc[i][1], acc[i][2], acc[i][3]};
        size_t base = (((size_t)mc * B_ + b) * N_ + n) * D_ + d0 + tx * 4;
        *(float4*)&part[base] = v;
    }
}

// ---------------------------------------------------------------------------
// K4: per-expert linear. Block = (n, e-half of 256). e = e0 + tid.
// ys[b][n][e] = sum_d (sum_mc part[mc][b][n][d]) / colsum[b][n] * W[n][d][e] + bias[n][e]
__global__ __launch_bounds__(256) void k_ys(const float* __restrict__ part,
                                            const float* __restrict__ colsum,
                                            const float* __restrict__ W,
                                            const float* __restrict__ bias,
                                            float* __restrict__ ys) {
    __shared__ float xsn[B_][D_];
    int bi = blockIdx.x;
    int n = bi >> 1, eh = bi & 1;
    int e0 = eh * 256;
    int tid = threadIdx.x;
    float inv[B_];
#pragma unroll
    for (int b = 0; b < B_; b++) inv[b] = 1.0f / colsum[b * N_ + n];
    for (int idx = tid; idx < B_ * D_; idx += 256) {
        int bb = idx >> 9, d = idx & 511;
        float s = 0.f;
#pragma unroll
        for (int mc = 0; mc < MCHUNKS; mc++)
            s += part[(((size_t)mc * B_ + bb) * N_ + n) * D_ + d];
        xsn[bb][d] = s * inv[bb];
    }
    __syncthreads();
    int e = e0 + tid;
    const float* Wn = W + (size_t)n * D_ * D_ + e;
    float a0 = 0.f, a1 = 0.f, a2 = 0.f, a3 = 0.f;
#pragma unroll 16
    for (int d = 0; d < D_; d++) {
        float w = Wn[(size_t)d * D_];
        a0 += xsn[0][d] * w;
        a1 += xsn[1][d] * w;
        a2 += xsn[2][d] * w;
        a3 += xsn[3][d] * w;
    }
    float bv = bias[n * D_ + e];
    ys[((size_t)0 * N_ + n) * D_ + e] = a0 + bv;
    ys[((size_t)1 * N_ + n) * D_ + e] = a1 + bv;
    ys[((size_t)2 * N_ + n) * D_ + e] = a2 + bv;
    ys[((size_t)3 * N_ + n) * D_ + e] = a3 + bv;
}

// ---------------------------------------------------------------------------
// K5: combine. Block = (token-tile of 32, e-tile of 128). Row-softmax of E
// fused; y[r][e] = sum_n (E[r][n]/rowsum[r]) * ys[b][n][e].
// 256 threads: ty=tid>>5 (m rows ty*4..+3), tx=tid&31 (e cols tx*4..+3).
__global__ __launch_bounds__(256) void k_combine(const float* __restrict__ E,
                                                 const float* __restrict__ ys,
                                                 float* __restrict__ y) {
    __shared__ float Ew[32][128];
    __shared__ float yst[16][128];
    __shared__ float red[32][8];
    __shared__ float sinv[32];
    int bi = blockIdx.x;
    int et = bi & 3, tt = bi >> 2;
    int r0 = tt * 32;
    int b = r0 >> 13;
    int e0 = et * 128;
    int tid = threadIdx.x;
#pragma unroll
    for (int i = 0; i < 4; i++) {
        int f = tid + i * 256;
        int row = f >> 5, c4 = f & 31;
        *(float4*)&Ew[row][c4 * 4] = *(const float4*)&E[(size_t)(r0 + row) * N_ + c4 * 4];
    }
    __syncthreads();
    {
        int row = tid >> 3, seg = tid & 7;
        float s = 0.f;
#pragma unroll
        for (int k = 0; k < 16; k++) s += Ew[row][seg * 16 + k];
        red[row][seg] = s;
    }
    __syncthreads();
    if (tid < 32) {
        float s = 0.f;
#pragma unroll
        for (int g = 0; g < 8; g++) s += red[tid][g];
        sinv[tid] = 1.0f / s;
    }
    __syncthreads();
#pragma unroll
    for (int i = 0; i < 4; i++) {
        int f = tid + i * 256;
        int row = f >> 5, c4 = f & 31;
        float iv = sinv[row];
        float4* p = (float4*)&Ew[row][c4 * 4];
        p->x *= iv; p->y *= iv; p->z *= iv; p->w *= iv;
    }
    __syncthreads();
    int ty = tid >> 5, tx = tid & 31;
    float acc[4][4];
#pragma unroll
    for (int i = 0; i < 4; i++)
#pragma unroll
        for (int j = 0; j < 4; j++) acc[i][j] = 0.f;
    for (int n0 = 0; n0 < N_; n0 += 16) {
#pragma unroll
        for (int i = 0; i < 2; i++) {
            int f = tid + i * 256;
            int kk = f >> 5, c4 = f & 31;
            *(float4*)&yst[kk][c4 * 4] =
                *(const float4*)&ys[((size_t)b * N_ + n0 + kk) * D_ + e0 + c4 * 4];
        }
        __syncthreads();
#pragma unroll
        for (int kk = 0; kk < 16; kk++) {
            float a[4];
#pragma unroll
            for (int i = 0; i < 4; i++) a[i] = Ew[ty * 4 + i][n0 + kk];
            float4 bv = *(float4*)&yst[kk][tx * 4];
#pragma unroll
            for (int i = 0; i < 4; i++) {
                acc[i][0] += a[i] * bv.x;
                acc[i][1] += a[i] * bv.y;
                acc[i][2] += a[i] * bv.z;
                acc[i][3] += a[i] * bv.w;
            }
        }
        __syncthreads();
    }
#pragma unroll
    for (int i = 0; i < 4; i++) {
        int r = r0 + ty * 4 + i;
        float4 v = {acc[i][0], acc[i][1], acc[i][2], acc[i][3]};
        *(float4*)&y[(size_t)r * D_ + e0 + tx * 4] = v;
    }
}

// ---------------------------------------------------------------------------
extern "C" void kernel_launch(void* const* d_in, const int* in_sizes, int n_in,
                              void* d_out, int out_size, void* d_ws, size_t ws_size,
                              hipStream_t stream) {
    const float* x = (const float*)d_in[0];      // [B,M,D]
    const float* phi = (const float*)d_in[1];    // [D,N,P=1]
    const float* scale = (const float*)d_in[2];  // [1]
    const float* W = (const float*)d_in[3];      // [N,D,D]
    const float* bias = (const float*)d_in[4];   // [N,D]
    float* y = (float*)d_out;                    // [B,M,D]
    float* ws = (float*)d_ws;

    float* rn = ws + OFF_RN;
    float* pb = ws + OFF_PB;
    float* colsum = ws + OFF_CS;
    float* part = ws + OFF_XP;
    float* ys = ws + OFF_YS;
    float* E = ws + OFF_E;

    // zero the colsum accumulator (ws is poisoned 0xAA before every launch)
    hipMemsetAsync(colsum, 0, B_ * N_ * sizeof(float), stream);

    k_phinorm<<<N_, 128, 0, stream>>>(phi, scale, pb);
    k_rn<<<TOK / 4, 256, 0, stream>>>(x, rn);
    k_logits<<<TOK / 64, 256, 0, stream>>>(x, pb, rn, E, colsum);
    k_xs<<<B_ * 8 * MCHUNKS, 256, 0, stream>>>(x, E, rn, part);
    k_ys<<<N_ * 2, 256, 0, stream>>>(part, colsum, W, bias, ys);
    k_combine<<<(TOK / 32) * 4, 256, 0, stream>>>(E, ys, y);
}

// Round 2
// 455.049 us; speedup vs baseline: 1.1128x; 1.1128x over previous
//
#include <hip/hip_runtime.h>
#include <math.h>

// Problem constants (fixed by setup_inputs): B=4, M=8192, D=512, N=128, P=1
#define B_ 4
#define M_ 8192
#define D_ 512
#define N_ 128
#define TOK (B_ * M_)   // 32768 token rows
#define MC_ 32          // split-K chunks over M for xs
#define MLEN (M_ / MC_) // 256 rows per chunk

// Workspace layout (float offsets)
#define OFF_RN 0                                  // [TOK] token inverse norms
#define OFF_PB (OFF_RN + TOK)                     // [D*N] normalized phi
#define OFF_CS (OFF_PB + D_ * N_)                 // [B*N] colsum of raw exp
#define OFF_XS (OFF_CS + B_ * N_)                 // [B*N*D] reduced+normalized xs
#define OFF_YS (OFF_XS + B_ * N_ * D_)            // [B*N*D] expert outputs
#define OFF_XP (OFF_YS + B_ * N_ * D_)            // [MC*B*N*D] xs partials
#define OFF_E (OFF_XP + MC_ * B_ * N_ * D_)       // [TOK*N] E' = exp(logit)*rn

// ---------------------------------------------------------------------------
// K0: phi column norms -> pb[d][n] = phi[d][n] * scale / max(||phi[:,n]||,eps)
__global__ __launch_bounds__(128) void k_phinorm(const float* __restrict__ phi,
                                                 const float* __restrict__ scale,
                                                 float* __restrict__ pb) {
    __shared__ float sred[128];
    int n = blockIdx.x, tid = threadIdx.x;
    float ss = 0.f;
    for (int d = tid; d < D_; d += 128) {
        float v = phi[d * N_ + n];
        ss += v * v;
    }
    sred[tid] = ss;
    __syncthreads();
    for (int s = 64; s > 0; s >>= 1) {
        if (tid < s) sred[tid] += sred[tid + s];
        __syncthreads();
    }
    float sc = scale[0] / fmaxf(sqrtf(sred[0]), 1e-12f);
    for (int d = tid; d < D_; d += 128) pb[d * N_ + n] = phi[d * N_ + n] * sc;
}

// ---------------------------------------------------------------------------
// K1: token inverse norms. One wave per token, 4 tokens/block.
__global__ __launch_bounds__(256) void k_rn(const float* __restrict__ x,
                                            float* __restrict__ rn) {
    int token = blockIdx.x * 4 + (threadIdx.x >> 6);
    int lane = threadIdx.x & 63;
    const float4* x4 = (const float4*)x;
    float4 a = x4[(size_t)token * 128 + lane];
    float4 c = x4[(size_t)token * 128 + 64 + lane];
    float ss = a.x * a.x + a.y * a.y + a.z * a.z + a.w * a.w +
               c.x * c.x + c.y * c.y + c.z * c.z + c.w * c.w;
#pragma unroll
    for (int off = 32; off > 0; off >>= 1) ss += __shfl_down(ss, off, 64);
    if (lane == 0) rn[token] = 1.0f / fmaxf(sqrtf(ss), 1e-12f);
}

// ---------------------------------------------------------------------------
// K2: logits GEMM + exp + colsum. Tile 128m x 64n, thread 8m x 4n.
// Stores E' = exp(logit) * rn[m]; colsum accumulates raw exp.
__global__ __launch_bounds__(256) void k_logits(const float* __restrict__ x,
                                                const float* __restrict__ pb,
                                                const float* __restrict__ rn,
                                                float* __restrict__ E,
                                                float* __restrict__ colsum) {
    __shared__ float At[16][128];  // [k][m], rn-scaled
    __shared__ float Bt[16][64];   // [k][n]
    __shared__ float scr[16][64];
    int tid = threadIdx.x, bi = blockIdx.x;
    int r0 = (bi >> 1) * 128;
    int n0 = (bi & 1) * 64;
    // A loader: row lm, k-half lkh (8 consecutive k)
    int lm = tid >> 1, lkh = (tid & 1) * 8;
    float rnv = rn[r0 + lm];
    // B loader
    int bkk = tid >> 4, bn4 = (tid & 15) * 4;
    // compute roles
    int ty = tid >> 4, tx = tid & 15;
    float acc[8][4];
#pragma unroll
    for (int i = 0; i < 8; i++)
#pragma unroll
        for (int j = 0; j < 4; j++) acc[i][j] = 0.f;

    for (int k0 = 0; k0 < D_; k0 += 16) {
        float4 a0 = *(const float4*)&x[(size_t)(r0 + lm) * D_ + k0 + lkh];
        float4 a1 = *(const float4*)&x[(size_t)(r0 + lm) * D_ + k0 + lkh + 4];
        At[lkh + 0][lm] = a0.x * rnv;
        At[lkh + 1][lm] = a0.y * rnv;
        At[lkh + 2][lm] = a0.z * rnv;
        At[lkh + 3][lm] = a0.w * rnv;
        At[lkh + 4][lm] = a1.x * rnv;
        At[lkh + 5][lm] = a1.y * rnv;
        At[lkh + 6][lm] = a1.z * rnv;
        At[lkh + 7][lm] = a1.w * rnv;
        *(float4*)&Bt[bkk][bn4] = *(const float4*)&pb[(size_t)(k0 + bkk) * N_ + n0 + bn4];
        __syncthreads();
#pragma unroll
        for (int kk = 0; kk < 16; kk++) {
            float4 av0 = *(float4*)&At[kk][ty * 4];
            float4 av1 = *(float4*)&At[kk][64 + ty * 4];
            float4 bv = *(float4*)&Bt[kk][tx * 4];
            float a8[8] = {av0.x, av0.y, av0.z, av0.w, av1.x, av1.y, av1.z, av1.w};
            float b4[4] = {bv.x, bv.y, bv.z, bv.w};
#pragma unroll
            for (int i = 0; i < 8; i++)
#pragma unroll
                for (int j = 0; j < 4; j++) acc[i][j] += a8[i] * b4[j];
        }
        __syncthreads();
    }
    // epilogue: exp, store E', colsum partials
    float csum[4] = {0.f, 0.f, 0.f, 0.f};
#pragma unroll
    for (int i = 0; i < 8; i++) {
        int m = (i < 4) ? (ty * 4 + i) : (64 + ty * 4 + (i - 4));
        float rr = rn[r0 + m];
        float e0 = __expf(acc[i][0]);
        float e1 = __expf(acc[i][1]);
        float e2 = __expf(acc[i][2]);
        float e3 = __expf(acc[i][3]);
        csum[0] += e0; csum[1] += e1; csum[2] += e2; csum[3] += e3;
        float4 v = {e0 * rr, e1 * rr, e2 * rr, e3 * rr};
        *(float4*)&E[(size_t)(r0 + m) * N_ + n0 + tx * 4] = v;
    }
#pragma unroll
    for (int j = 0; j < 4; j++) scr[ty][tx * 4 + j] = csum[j];
    __syncthreads();
    if (tid < 64) {
        float s = 0.f;
#pragma unroll
        for (int g = 0; g < 16; g++) s += scr[g][tid];
        int b = r0 >> 13;
        atomicAdd(&colsum[b * N_ + n0 + tid], s);
    }
}

// ---------------------------------------------------------------------------
// K3: xs partials. Grid = b(4) x mc(32) x dt(4). Tile 128n x 128d, thread 8x8.
// part[mc][b][n][d] = sum_{m in chunk} E'[m][n] * x[m][d]
__global__ __launch_bounds__(256) void k_xs(const float* __restrict__ x,
                                            const float* __restrict__ E,
                                            float* __restrict__ part) {
    __shared__ float Et[16][128];  // [m][n]
    __shared__ float xt[16][128];  // [m][d]
    int tid = threadIdx.x, bi = blockIdx.x;
    int dt = bi & 3, mc = (bi >> 2) & 31, b = bi >> 7;
    int d0 = dt * 128;
    int rbase = b * M_ + mc * MLEN;
    int lmm = tid >> 4, lc4 = (tid & 15) * 4;
    int ty = tid >> 4, tx = tid & 15;
    float acc[8][8];
#pragma unroll
    for (int i = 0; i < 8; i++)
#pragma unroll
        for (int j = 0; j < 8; j++) acc[i][j] = 0.f;

    for (int ms = 0; ms < MLEN; ms += 16) {
        int rb = rbase + ms;
        const float* Er = &E[(size_t)(rb + lmm) * N_];
        const float* xr = &x[(size_t)(rb + lmm) * D_ + d0];
        *(float4*)&Et[lmm][lc4] = *(const float4*)&Er[lc4];
        *(float4*)&Et[lmm][64 + lc4] = *(const float4*)&Er[64 + lc4];
        *(float4*)&xt[lmm][lc4] = *(const float4*)&xr[lc4];
        *(float4*)&xt[lmm][64 + lc4] = *(const float4*)&xr[64 + lc4];
        __syncthreads();
#pragma unroll
        for (int kk = 0; kk < 16; kk++) {
            float4 a0 = *(float4*)&Et[kk][ty * 4];
            float4 a1 = *(float4*)&Et[kk][64 + ty * 4];
            float4 b0 = *(float4*)&xt[kk][tx * 4];
            float4 b1 = *(float4*)&xt[kk][64 + tx * 4];
            float a8[8] = {a0.x, a0.y, a0.z, a0.w, a1.x, a1.y, a1.z, a1.w};
            float b8[8] = {b0.x, b0.y, b0.z, b0.w, b1.x, b1.y, b1.z, b1.w};
#pragma unroll
            for (int i = 0; i < 8; i++)
#pragma unroll
                for (int j = 0; j < 8; j++) acc[i][j] += a8[i] * b8[j];
        }
        __syncthreads();
    }
#pragma unroll
    for (int i = 0; i < 8; i++) {
        int n = (i < 4) ? (ty * 4 + i) : (64 + ty * 4 + (i - 4));
        size_t base = (((size_t)mc * B_ + b) * N_ + n) * D_ + d0;
        float4 v0 = {acc[i][0], acc[i][1], acc[i][2], acc[i][3]};
        float4 v1 = {acc[i][4], acc[i][5], acc[i][6], acc[i][7]};
        *(float4*)&part[base + tx * 4] = v0;
        *(float4*)&part[base + 64 + tx * 4] = v1;
    }
}

// ---------------------------------------------------------------------------
// K3b: reduce partials over mc and normalize by colsum -> xs[b][n][d]
__global__ __launch_bounds__(256) void k_xsum(const float* __restrict__ part,
                                              const float* __restrict__ colsum,
                                              float* __restrict__ xs) {
    int bi = blockIdx.x;  // = b*N + n
    int tid = threadIdx.x;
    float inv = 1.0f / colsum[bi];
    size_t base = (size_t)bi * D_ + tid * 2;
    float sx = 0.f, sy = 0.f;
#pragma unroll 8
    for (int mc = 0; mc < MC_; mc++) {
        float2 v = *(const float2*)&part[(size_t)mc * (B_ * N_ * D_) + base];
        sx += v.x;
        sy += v.y;
    }
    float2 o = {sx * inv, sy * inv};
    *(float2*)&xs[base] = o;
}

// ---------------------------------------------------------------------------
// K4: per-expert linear. Grid = n(128) x eq(4). 256 thr: b = tid>>6, e pair.
__global__ __launch_bounds__(256) void k_ys(const float* __restrict__ xs,
                                            const float* __restrict__ W,
                                            const float* __restrict__ bias,
                                            float* __restrict__ ys) {
    __shared__ float xsn[B_][D_];
    int bi = blockIdx.x;
    int n = bi >> 2, eq = bi & 3;
    int tid = threadIdx.x;
    {
        int lb = tid >> 6, ld = (tid & 63) * 4;
        *(float4*)&xsn[lb][ld] = *(const float4*)&xs[((size_t)lb * N_ + n) * D_ + ld];
        *(float4*)&xsn[lb][256 + ld] =
            *(const float4*)&xs[((size_t)lb * N_ + n) * D_ + 256 + ld];
    }
    __syncthreads();
    int b = tid >> 6;
    int e = eq * 128 + (tid & 63) * 2;
    const float* Wn = W + (size_t)n * D_ * D_ + e;
    float a0 = 0.f, a1 = 0.f;
#pragma unroll 8
    for (int d = 0; d < D_; d++) {
        float2 w = *(const float2*)&Wn[(size_t)d * D_];
        float xv = xsn[b][d];
        a0 += xv * w.x;
        a1 += xv * w.y;
    }
    float2 bv = *(const float2*)&bias[n * D_ + e];
    float2 o = {a0 + bv.x, a1 + bv.y};
    *(float2*)&ys[((size_t)b * N_ + n) * D_ + e] = o;
}

// ---------------------------------------------------------------------------
// K5: combine. Tile 64m x 128e, thread 4m x 8e. Row-softmax denominator via
// global re-read + shuffle; 1/rowsum folded into the store.
__global__ __launch_bounds__(256) void k_combine(const float* __restrict__ E,
                                                 const float* __restrict__ ys,
                                                 float* __restrict__ y) {
    __shared__ float Ew[64][132];  // pad 4: bank stride 4/row, reads 2-way max
    __shared__ float yst[16][128];
    __shared__ float sinv[64];
    int tid = threadIdx.x, bi = blockIdx.x;
    int et = bi & 3, tt = bi >> 2;
    int r0 = tt * 64, b = r0 >> 13, e0 = et * 128;
    // load Ew [64][128]
#pragma unroll
    for (int i = 0; i < 4; i++) {
        int row = (tid >> 4) + i * 16;
        int c = (tid & 15) * 4;
        const float* er = &E[(size_t)(r0 + row) * N_];
        *(float4*)&Ew[row][c] = *(const float4*)&er[c];
        *(float4*)&Ew[row][64 + c] = *(const float4*)&er[64 + c];
    }
    // row sums from global (L2-hot) + 4-lane shuffle reduce
    {
        int row = tid >> 2, seg = tid & 3;
        const float* er = &E[(size_t)(r0 + row) * N_ + seg * 32];
        float s = 0.f;
#pragma unroll
        for (int q = 0; q < 8; q++) {
            float4 v = *(const float4*)&er[q * 4];
            s += v.x + v.y + v.z + v.w;
        }
        s += __shfl_xor(s, 1, 64);
        s += __shfl_xor(s, 2, 64);
        if (seg == 0) sinv[row] = 1.0f / s;
    }
    int ty = tid >> 4, tx = tid & 15;
    float acc[4][8];
#pragma unroll
    for (int i = 0; i < 4; i++)
#pragma unroll
        for (int j = 0; j < 8; j++) acc[i][j] = 0.f;
    int lkk = tid >> 4, lc = (tid & 15) * 4;
    for (int n0 = 0; n0 < N_; n0 += 16) {
        __syncthreads();  // first iter: covers Ew/sinv; later: yst reuse guard
        const float* yr = &ys[((size_t)b * N_ + n0 + lkk) * D_ + e0];
        *(float4*)&yst[lkk][lc] = *(const float4*)&yr[lc];
        *(float4*)&yst[lkk][64 + lc] = *(const float4*)&yr[64 + lc];
        __syncthreads();
#pragma unroll
        for (int kk = 0; kk < 16; kk++) {
            float a4[4];
#pragma unroll
            for (int i = 0; i < 4; i++) a4[i] = Ew[ty * 4 + i][n0 + kk];
            float4 b0 = *(float4*)&yst[kk][tx * 4];
            float4 b1 = *(float4*)&yst[kk][64 + tx * 4];
            float b8[8] = {b0.x, b0.y, b0.z, b0.w, b1.x, b1.y, b1.z, b1.w};
#pragma unroll
            for (int i = 0; i < 4; i++)
#pragma unroll
                for (int j = 0; j < 8; j++) acc[i][j] += a4[i] * b8[j];
        }
    }
#pragma unroll
    for (int i = 0; i < 4; i++) {
        int m = ty * 4 + i;
        float sv = sinv[m];
        float4 v0 = {acc[i][0] * sv, acc[i][1] * sv, acc[i][2] * sv, acc[i][3] * sv};
        float4 v1 = {acc[i][4] * sv, acc[i][5] * sv, acc[i][6] * sv, acc[i][7] * sv};
        float* yr = &y[(size_t)(r0 + m) * D_ + e0];
        *(float4*)&yr[tx * 4] = v0;
        *(float4*)&yr[64 + tx * 4] = v1;
    }
}

// ---------------------------------------------------------------------------
extern "C" void kernel_launch(void* const* d_in, const int* in_sizes, int n_in,
                              void* d_out, int out_size, void* d_ws, size_t ws_size,
                              hipStream_t stream) {
    const float* x = (const float*)d_in[0];
    const float* phi = (const float*)d_in[1];
    const float* scale = (const float*)d_in[2];
    const float* W = (const float*)d_in[3];
    const float* bias = (const float*)d_in[4];
    float* y = (float*)d_out;
    float* ws = (float*)d_ws;

    float* rn = ws + OFF_RN;
    float* pb = ws + OFF_PB;
    float* colsum = ws + OFF_CS;
    float* xs = ws + OFF_XS;
    float* ysb = ws + OFF_YS;
    float* part = ws + OFF_XP;
    float* E = ws + OFF_E;

    hipMemsetAsync(colsum, 0, B_ * N_ * sizeof(float), stream);

    k_phinorm<<<N_, 128, 0, stream>>>(phi, scale, pb);
    k_rn<<<TOK / 4, 256, 0, stream>>>(x, rn);
    k_logits<<<(TOK / 128) * 2, 256, 0, stream>>>(x, pb, rn, E, colsum);
    k_xs<<<B_ * MC_ * 4, 256, 0, stream>>>(x, E, part);
    k_xsum<<<B_ * N_, 256, 0, stream>>>(part, colsum, xs);
    k_ys<<<N_ * 4, 256, 0, stream>>>(xs, W, bias, ysb);
    k_combine<<<(TOK / 64) * 4, 256, 0, stream>>>(E, ysb, y);
}

// Round 3
// 375.917 us; speedup vs baseline: 1.3470x; 1.2105x over previous
//
#include <hip/hip_runtime.h>
#include <math.h>

// Problem constants: B=4, M=8192, D=512, N=128, P=1
#define B_ 4
#define M_ 8192
#define D_ 512
#define N_ 128
#define TOK (B_ * M_)    // 32768
#define MC_ 64           // split-K chunks over M for xs
#define MLEN (M_ / MC_)  // 128 rows per chunk

// Workspace layout (float offsets)
#define OFF_RN 0                         // [32768] token inverse norms
#define OFF_CS (OFF_RN + TOK)            // [512] colsum of raw exp
#define OFF_XS (OFF_CS + 512)            // [B*N*D] normalized slot inputs
#define OFF_YS (OFF_XS + B_ * N_ * D_)   // [B*N*D] expert outputs fp32
#define OFF_PBT (OFF_YS + B_ * N_ * D_)  // [N*D] bf16 (as shorts, 32768 f-slots)
#define OFF_YST (OFF_PBT + N_ * D_ / 2)  // [B*D*N] bf16 (131072 f-slots)
#define OFF_E (OFF_YST + B_ * D_ * N_ / 2)  // [TOK*N] raw exp(logits) fp32
#define OFF_XP (OFF_E + (size_t)TOK * N_)   // [MC*B*N*D] xs partials

typedef __attribute__((ext_vector_type(8))) short s16x8;
typedef __attribute__((ext_vector_type(4))) float f32x4;

__device__ inline short f2bf(float f) {  // RNE round to bf16
    union { float f; unsigned u; } v;
    v.f = f;
    unsigned r = v.u + 0x7fffu + ((v.u >> 16) & 1u);
    return (short)(r >> 16);
}

// ---------------------------------------------------------------------------
// K0: phi col-normalize -> pbt[n][d] bf16 = scale * phi[d][n]/max(||phi[:,n]||,eps)
__global__ __launch_bounds__(128) void k_phinorm(const float* __restrict__ phi,
                                                 const float* __restrict__ scale,
                                                 short* __restrict__ pbt) {
    __shared__ float sred[128];
    int n = blockIdx.x, tid = threadIdx.x;
    float ss = 0.f;
    for (int d = tid; d < D_; d += 128) {
        float v = phi[d * N_ + n];
        ss += v * v;
    }
    sred[tid] = ss;
    __syncthreads();
    for (int s = 64; s > 0; s >>= 1) {
        if (tid < s) sred[tid] += sred[tid + s];
        __syncthreads();
    }
    float sc = scale[0] / fmaxf(sqrtf(sred[0]), 1e-12f);
    for (int d = tid; d < D_; d += 128) pbt[n * D_ + d] = f2bf(phi[d * N_ + n] * sc);
}

// ---------------------------------------------------------------------------
// K1: token inverse norms.
__global__ __launch_bounds__(256) void k_rn(const float* __restrict__ x,
                                            float* __restrict__ rn) {
    int token = blockIdx.x * 4 + (threadIdx.x >> 6);
    int lane = threadIdx.x & 63;
    const float4* x4 = (const float4*)x;
    float4 a = x4[(size_t)token * 128 + lane];
    float4 c = x4[(size_t)token * 128 + 64 + lane];
    float ss = a.x * a.x + a.y * a.y + a.z * a.z + a.w * a.w +
               c.x * c.x + c.y * c.y + c.z * c.z + c.w * c.w;
#pragma unroll
    for (int off = 32; off > 0; off >>= 1) ss += __shfl_down(ss, off, 64);
    if (lane == 0) rn[token] = 1.0f / fmaxf(sqrtf(ss), 1e-12f);
}

// ---------------------------------------------------------------------------
// K2: logits via bf16 MFMA. Block: 128m x 128n, 512 thr (8 waves, 4x2).
// E[m][n] = exp(dot(x[m]*rn[m], pb[:,n])) (raw exp); colsum += raw exp.
__global__ __launch_bounds__(512) void k_logits(const float* __restrict__ x,
                                                const short* __restrict__ pbt,
                                                const float* __restrict__ rn,
                                                float* __restrict__ E,
                                                float* __restrict__ colsum) {
    __shared__ short As[128 * 40];  // [m][k0..31], stride 40 (80B rows, 16B-aligned)
    __shared__ short Bs[128 * 40];  // [n][k0..31]
    int t = threadIdx.x;
    int r0 = blockIdx.x * 128;
    int sm = t >> 2;           // staging row (m for A, n for B)
    int kq = (t & 3) * 8;      // k sub-chunk
    float rnv = rn[r0 + sm];
    const float* xrow = &x[(size_t)(r0 + sm) * D_ + kq];
    const short* brow = &pbt[sm * D_ + kq];
    int wid = t >> 6, lane = t & 63;
    int quad = lane >> 4, l15 = lane & 15;
    int mw = (wid >> 1) * 32, nw = (wid & 1) * 64;
    f32x4 acc[2][4] = {};

    for (int k0 = 0; k0 < D_; k0 += 32) {
        float4 a0 = *(const float4*)&xrow[k0];
        float4 a1 = *(const float4*)&xrow[k0 + 4];
        s16x8 bv = *(const s16x8*)&brow[k0];
        short4 w0 = {f2bf(a0.x * rnv), f2bf(a0.y * rnv), f2bf(a0.z * rnv), f2bf(a0.w * rnv)};
        short4 w1 = {f2bf(a1.x * rnv), f2bf(a1.y * rnv), f2bf(a1.z * rnv), f2bf(a1.w * rnv)};
        *(short4*)&As[sm * 40 + kq] = w0;
        *(short4*)&As[sm * 40 + kq + 4] = w1;
        *(s16x8*)&Bs[sm * 40 + kq] = bv;
        __syncthreads();
        s16x8 af[2], bf[4];
#pragma unroll
        for (int i = 0; i < 2; i++)
            af[i] = *(const s16x8*)&As[(mw + i * 16 + l15) * 40 + quad * 8];
#pragma unroll
        for (int j = 0; j < 4; j++)
            bf[j] = *(const s16x8*)&Bs[(nw + j * 16 + l15) * 40 + quad * 8];
#pragma unroll
        for (int i = 0; i < 2; i++)
#pragma unroll
            for (int j = 0; j < 4; j++)
                acc[i][j] = __builtin_amdgcn_mfma_f32_16x16x32_bf16(af[i], bf[j], acc[i][j], 0, 0, 0);
        __syncthreads();
    }
    int bb = r0 >> 13;
#pragma unroll
    for (int j = 0; j < 4; j++) {
        int n = nw + j * 16 + l15;
        float cs = 0.f;
#pragma unroll
        for (int i = 0; i < 2; i++) {
            int mb = r0 + mw + i * 16 + quad * 4;
            f32x4 v = acc[i][j];
            float e0 = __expf(v[0]), e1 = __expf(v[1]), e2 = __expf(v[2]), e3 = __expf(v[3]);
            cs += e0 + e1 + e2 + e3;
            E[(size_t)(mb + 0) * N_ + n] = e0;
            E[(size_t)(mb + 1) * N_ + n] = e1;
            E[(size_t)(mb + 2) * N_ + n] = e2;
            E[(size_t)(mb + 3) * N_ + n] = e3;
        }
        cs += __shfl_xor(cs, 16, 64);
        cs += __shfl_xor(cs, 32, 64);
        if (lane < 16) atomicAdd(&colsum[bb * N_ + n], cs);
    }
}

// ---------------------------------------------------------------------------
// K3: xs partials (fp32). Grid b(4) x mc(64) x dt(4), tile 128n x 128d, thr 8x8.
// part[mc][b][n][d] = sum_m (E[m][n]*rn[m]) * x[m][d]
__global__ __launch_bounds__(256) void k_xs(const float* __restrict__ x,
                                            const float* __restrict__ E,
                                            const float* __restrict__ rn,
                                            float* __restrict__ part) {
    __shared__ float Et[16][128];
    __shared__ float xt[16][128];
    int tid = threadIdx.x, bi = blockIdx.x;
    int dt = bi & 3, mc = (bi >> 2) & 63, b = bi >> 8;
    int d0 = dt * 128;
    int rbase = b * M_ + mc * MLEN;
    int ty = tid >> 4, tx = tid & 15;
    float acc[8][8];
#pragma unroll
    for (int i = 0; i < 8; i++)
#pragma unroll
        for (int j = 0; j < 8; j++) acc[i][j] = 0.f;

    for (int ms = 0; ms < MLEN; ms += 16) {
        int rb = rbase + ms;
        {
            int lmm = tid >> 4, lc4 = (tid & 15) * 4;
            float rr = rn[rb + lmm];
            const float* Er = &E[(size_t)(rb + lmm) * N_];
            const float* xr = &x[(size_t)(rb + lmm) * D_ + d0];
            float4 v0 = *(const float4*)&Er[lc4];
            float4 v1 = *(const float4*)&Er[64 + lc4];
            v0.x *= rr; v0.y *= rr; v0.z *= rr; v0.w *= rr;
            v1.x *= rr; v1.y *= rr; v1.z *= rr; v1.w *= rr;
            *(float4*)&Et[lmm][lc4] = v0;
            *(float4*)&Et[lmm][64 + lc4] = v1;
            *(float4*)&xt[lmm][lc4] = *(const float4*)&xr[lc4];
            *(float4*)&xt[lmm][64 + lc4] = *(const float4*)&xr[64 + lc4];
        }
        __syncthreads();
#pragma unroll
        for (int kk = 0; kk < 16; kk++) {
            float4 a0 = *(float4*)&Et[kk][ty * 4];
            float4 a1 = *(float4*)&Et[kk][64 + ty * 4];
            float4 b0 = *(float4*)&xt[kk][tx * 4];
            float4 b1 = *(float4*)&xt[kk][64 + tx * 4];
            float a8[8] = {a0.x, a0.y, a0.z, a0.w, a1.x, a1.y, a1.z, a1.w};
            float b8[8] = {b0.x, b0.y, b0.z, b0.w, b1.x, b1.y, b1.z, b1.w};
#pragma unroll
            for (int i = 0; i < 8; i++)
#pragma unroll
                for (int j = 0; j < 8; j++) acc[i][j] += a8[i] * b8[j];
        }
        __syncthreads();
    }
#pragma unroll
    for (int i = 0; i < 8; i++) {
        int n = (i < 4) ? (ty * 4 + i) : (64 + ty * 4 + (i - 4));
        size_t base = (((size_t)mc * B_ + b) * N_ + n) * D_ + d0;
        float4 v0 = {acc[i][0], acc[i][1], acc[i][2], acc[i][3]};
        float4 v1 = {acc[i][4], acc[i][5], acc[i][6], acc[i][7]};
        *(float4*)&part[base + tx * 4] = v0;
        *(float4*)&part[base + 64 + tx * 4] = v1;
    }
}

// ---------------------------------------------------------------------------
// K3b: reduce partials over mc, normalize by colsum -> xs[b][n][d]
__global__ __launch_bounds__(256) void k_xsum(const float* __restrict__ part,
                                              const float* __restrict__ colsum,
                                              float* __restrict__ xs) {
    int bi = blockIdx.x;  // b*N + n
    int tid = threadIdx.x;
    float inv = 1.0f / colsum[bi];
    size_t base = (size_t)bi * D_ + tid * 2;
    float sx = 0.f, sy = 0.f;
#pragma unroll 8
    for (int mc = 0; mc < MC_; mc++) {
        float2 v = *(const float2*)&part[(size_t)mc * (B_ * N_ * D_) + base];
        sx += v.x;
        sy += v.y;
    }
    float2 o = {sx * inv, sy * inv};
    *(float2*)&xs[base] = o;
}

// ---------------------------------------------------------------------------
// K4: per-expert linear (HBM-bound on W). Grid n(128) x eq(4).
__global__ __launch_bounds__(256) void k_ys(const float* __restrict__ xs,
                                            const float* __restrict__ W,
                                            const float* __restrict__ bias,
                                            float* __restrict__ ys) {
    __shared__ float xsn[B_][D_];
    int bi = blockIdx.x;
    int n = bi >> 2, eq = bi & 3;
    int tid = threadIdx.x;
    {
        int lb = tid >> 6, ld = (tid & 63) * 4;
        *(float4*)&xsn[lb][ld] = *(const float4*)&xs[((size_t)lb * N_ + n) * D_ + ld];
        *(float4*)&xsn[lb][256 + ld] =
            *(const float4*)&xs[((size_t)lb * N_ + n) * D_ + 256 + ld];
    }
    __syncthreads();
    int b = tid >> 6;
    int e = eq * 128 + (tid & 63) * 2;
    const float* Wn = W + (size_t)n * D_ * D_ + e;
    float a0 = 0.f, a1 = 0.f;
#pragma unroll 8
    for (int d = 0; d < D_; d++) {
        float2 w = *(const float2*)&Wn[(size_t)d * D_];
        float xv = xsn[b][d];
        a0 += xv * w.x;
        a1 += xv * w.y;
    }
    float2 bv = *(const float2*)&bias[n * D_ + e];
    float2 o = {a0 + bv.x, a1 + bv.y};
    *(float2*)&ys[((size_t)b * N_ + n) * D_ + e] = o;
}

// ---------------------------------------------------------------------------
// K4b: transpose ys fp32 [b][n][d] -> ysT bf16 [b][d][n]
__global__ __launch_bounds__(256) void k_yst(const float* __restrict__ ys,
                                             short* __restrict__ ysT) {
    __shared__ float tile[32][33];
    int bi = blockIdx.x;
    int nt = bi & 3, dt = (bi >> 2) & 15, b = bi >> 6;
    int n0 = nt * 32, d0 = dt * 32;
    int t = threadIdx.x;
    int r = t >> 3, c = (t & 7) * 4;
    float4 v = *(const float4*)&ys[((size_t)b * N_ + n0 + r) * D_ + d0 + c];
    tile[r][c] = v.x; tile[r][c + 1] = v.y; tile[r][c + 2] = v.z; tile[r][c + 3] = v.w;
    __syncthreads();
    short4 o = {f2bf(tile[c][r]), f2bf(tile[c + 1][r]), f2bf(tile[c + 2][r]),
                f2bf(tile[c + 3][r])};
    *(short4*)&ysT[((size_t)b * D_ + d0 + r) * N_ + n0 + c] = o;
}

// ---------------------------------------------------------------------------
// K5: combine via bf16 MFMA. Block: 128m x 128d, K=n=128 in 4 chunks of 32.
// y[m][d] = sum_n (E[m][n]/rowsum[m]) * ysT[d][n]; rowsum in fp32 from staging.
__global__ __launch_bounds__(256) void k_combine(const float* __restrict__ E,
                                                 const short* __restrict__ ysT,
                                                 float* __restrict__ y) {
    __shared__ short As[128 * 40];  // [m][n-chunk 0..31]
    __shared__ short Bs[128 * 40];  // [d][n-chunk 0..31]
    __shared__ float rsA[2][128];
    __shared__ float rsinv[128];
    int t = threadIdx.x, bi = blockIdx.x;
    int dt = bi & 3, mt = bi >> 2;
    int r0 = mt * 128, d0 = dt * 128;
    int bb = r0 >> 13;
    int sm = t >> 1, nh = (t & 1) * 16;
    const float* erow = &E[(size_t)(r0 + sm) * N_ + nh];
    const short* yrow = &ysT[((size_t)bb * D_ + d0 + sm) * N_ + nh];
    int wid = t >> 6, lane = t & 63;
    int quad = lane >> 4, l15 = lane & 15;
    int mw = (wid >> 1) * 64, dw = (wid & 1) * 64;
    f32x4 acc[4][4] = {};
    float rsp = 0.f;

    for (int ks = 0; ks < 4; ks++) {
        int n0 = ks * 32;
        float4 e0 = *(const float4*)&erow[n0];
        float4 e1 = *(const float4*)&erow[n0 + 4];
        float4 e2 = *(const float4*)&erow[n0 + 8];
        float4 e3 = *(const float4*)&erow[n0 + 12];
        rsp += e0.x + e0.y + e0.z + e0.w + e1.x + e1.y + e1.z + e1.w +
               e2.x + e2.y + e2.z + e2.w + e3.x + e3.y + e3.z + e3.w;
        short4 w0 = {f2bf(e0.x), f2bf(e0.y), f2bf(e0.z), f2bf(e0.w)};
        short4 w1 = {f2bf(e1.x), f2bf(e1.y), f2bf(e1.z), f2bf(e1.w)};
        short4 w2 = {f2bf(e2.x), f2bf(e2.y), f2bf(e2.z), f2bf(e2.w)};
        short4 w3 = {f2bf(e3.x), f2bf(e3.y), f2bf(e3.z), f2bf(e3.w)};
        *(short4*)&As[sm * 40 + nh + 0] = w0;
        *(short4*)&As[sm * 40 + nh + 4] = w1;
        *(short4*)&As[sm * 40 + nh + 8] = w2;
        *(short4*)&As[sm * 40 + nh + 12] = w3;
        *(s16x8*)&Bs[sm * 40 + nh] = *(const s16x8*)&yrow[n0];
        *(s16x8*)&Bs[sm * 40 + nh + 8] = *(const s16x8*)&yrow[n0 + 8];
        __syncthreads();
        s16x8 af[4], bf[4];
#pragma unroll
        for (int i = 0; i < 4; i++)
            af[i] = *(const s16x8*)&As[(mw + i * 16 + l15) * 40 + quad * 8];
#pragma unroll
        for (int j = 0; j < 4; j++)
            bf[j] = *(const s16x8*)&Bs[(dw + j * 16 + l15) * 40 + quad * 8];
#pragma unroll
        for (int i = 0; i < 4; i++)
#pragma unroll
            for (int j = 0; j < 4; j++)
                acc[i][j] = __builtin_amdgcn_mfma_f32_16x16x32_bf16(af[i], bf[j], acc[i][j], 0, 0, 0);
        __syncthreads();
    }
    rsA[t & 1][sm] = rsp;
    __syncthreads();
    if (t < 128) rsinv[t] = 1.0f / (rsA[0][t] + rsA[1][t]);
    __syncthreads();
#pragma unroll
    for (int i = 0; i < 4; i++) {
        int mb = mw + i * 16 + quad * 4;
        float i0 = rsinv[mb], i1 = rsinv[mb + 1], i2 = rsinv[mb + 2], i3 = rsinv[mb + 3];
#pragma unroll
        for (int j = 0; j < 4; j++) {
            int d = d0 + dw + j * 16 + l15;
            f32x4 v = acc[i][j];
            y[(size_t)(r0 + mb + 0) * D_ + d] = v[0] * i0;
            y[(size_t)(r0 + mb + 1) * D_ + d] = v[1] * i1;
            y[(size_t)(r0 + mb + 2) * D_ + d] = v[2] * i2;
            y[(size_t)(r0 + mb + 3) * D_ + d] = v[3] * i3;
        }
    }
}

// ---------------------------------------------------------------------------
extern "C" void kernel_launch(void* const* d_in, const int* in_sizes, int n_in,
                              void* d_out, int out_size, void* d_ws, size_t ws_size,
                              hipStream_t stream) {
    const float* x = (const float*)d_in[0];
    const float* phi = (const float*)d_in[1];
    const float* scale = (const float*)d_in[2];
    const float* W = (const float*)d_in[3];
    const float* bias = (const float*)d_in[4];
    float* y = (float*)d_out;
    float* ws = (float*)d_ws;

    float* rn = ws + OFF_RN;
    float* colsum = ws + OFF_CS;
    float* xs = ws + OFF_XS;
    float* ysb = ws + OFF_YS;
    short* pbt = (short*)(ws + OFF_PBT);
    short* ysT = (short*)(ws + OFF_YST);
    float* E = ws + OFF_E;
    float* part = ws + OFF_XP;

    hipMemsetAsync(colsum, 0, 512 * sizeof(float), stream);

    k_phinorm<<<N_, 128, 0, stream>>>(phi, scale, pbt);
    k_rn<<<TOK / 4, 256, 0, stream>>>(x, rn);
    k_logits<<<TOK / 128, 512, 0, stream>>>(x, pbt, rn, E, colsum);
    k_xs<<<B_ * MC_ * 4, 256, 0, stream>>>(x, E, rn, part);
    k_xsum<<<B_ * N_, 256, 0, stream>>>(part, colsum, xs);
    k_ys<<<N_ * 4, 256, 0, stream>>>(xs, W, bias, ysb);
    k_yst<<<B_ * 16 * 4, 256, 0, stream>>>(ysb, ysT);
    k_combine<<<(TOK / 128) * 4, 256, 0, stream>>>(E, ysT, y);
}